// Round 6
// baseline (50.296 us; speedup 1.0000x reference)
//
#include <hip/hip_runtime.h>

static constexpr int Bn = 256;
static constexpr int Ln = 4096;
static constexpr int Dn = 40;     // output dim
static constexpr int NU = 101;    // number of embedding rows
static constexpr float PADF = 39.0f;

static constexpr int NBLK = 2048;        // 8 blocks/CU, all co-resident
static constexpr int P_PROBS = 560;      // positions per pure-probs block
static constexpr int P_RLE   = 176;      // positions per rle block
static_assert((NBLK - Bn) * P_PROBS + Bn * P_RLE == Bn * Ln, "position split must cover exactly");

static constexpr int SMEM_BYTES = 18432;

typedef float f32x4 __attribute__((ext_vector_type(4)));

__device__ __forceinline__ void nt_store4(float4* p, float4 v) {
    f32x4 nv = {v.x, v.y, v.z, v.w};
    __builtin_nontemporal_store(nv, (f32x4*)p);
}

// One fused kernel, 2048 blocks:
//   blocks [0, Bn)    : RLE for row bid (labels/ded/inv), then small probs share
//   blocks [Bn, 2048) : probs share only
// All output stores are NONTEMPORAL (streaming, no L2 allocation): the output
// has zero on-device reuse, and the runtime's fill kernel demonstrates ~7 TB/s
// with streaming stores vs our ~5 TB/s with default write-back stores.
__global__ __launch_bounds__(256) void fused_kernel(const int* __restrict__ x,
                                                    const float* __restrict__ W,
                                                    float* __restrict__ out) {
    __shared__ __align__(16) char smem[SMEM_BYTES];
    // probs-phase layout:
    float4* sW4 = (float4*)smem;                     // 1010 f4 = 16160 B (scaled table)
    float*  sW  = (float*)smem;
    int*    sx  = (int*)(smem + 16160);              // up to 568 ints (needs <= 560)
    // rle-phase layout (aliased; phases separated by barriers):
    float*  sded  = (float*)smem;                    // 4096 f32 = 16384 B
    float4* sded4 = (float4*)smem;
    int*    slab  = (int*)(smem + 16384);            // 101 ints
    int*    wsum  = (int*)(smem + 16384 + 101 * 4);  // 4 ints

    float* probs  = out;
    float* labels = out + (size_t)Bn * Ln * Dn;
    float* ded    = labels + (size_t)Bn * Ln;
    float* inv    = ded + (size_t)Bn * Ln;

    const int tid = threadIdx.x;
    const int bid = blockIdx.x;

    int pbase, pcnt;
    if (bid < Bn) {
        // ================= RLE phase (row = bid) =================
        pbase = (NBLK - Bn) * P_PROBS + bid * P_RLE;
        pcnt = P_RLE;

        if (tid < NU) {
            const float* wr = W + tid * Dn;
            float ss = 0.f;
#pragma unroll
            for (int d = 0; d < Dn; ++d) { float v = wr[d]; ss += v * v; }
            float scale = fminf(1.0f, 1.0f / fmaxf(sqrtf(ss), 1e-12f));
            float best = -3.4e38f; int bi = 0;
#pragma unroll
            for (int d = 0; d < Dn; ++d) {
                float v = wr[d] * scale;               // argmax on SCALED values
                if (v > best) { best = v; bi = d; }    // strict > == jnp first-max
            }
            slab[tid] = bi;
        }
        {
            const float4 padv = make_float4(PADF, PADF, PADF, PADF);
            for (int i = tid; i < Ln / 4; i += 256) sded4[i] = padv;
        }
        __syncthreads();

        const int row = bid;
        const int* xr = x + row * Ln;
        const int t0 = tid * 16;

        int xv[16];
        const int4* xp = (const int4*)(xr + t0);
#pragma unroll
        for (int q = 0; q < 4; ++q) {
            int4 a = xp[q];
            xv[q * 4 + 0] = a.x; xv[q * 4 + 1] = a.y;
            xv[q * 4 + 2] = a.z; xv[q * 4 + 3] = a.w;
        }
        const int prevlab = (tid == 0) ? -1 : slab[xr[t0 - 1]];

        int lv[16]; int invloc[16];
        int run = prevlab; int cnt = 0;
#pragma unroll
        for (int j = 0; j < 16; ++j) {
            lv[j] = slab[xv[j]];
            cnt += (lv[j] != run) ? 1 : 0;
            invloc[j] = cnt;
            run = lv[j];
        }

        const int lane = tid & 63;
        const int wid = tid >> 6;
        int incl = cnt;
#pragma unroll
        for (int off = 1; off < 64; off <<= 1) {
            int v = __shfl_up(incl, off, 64);
            if (lane >= off) incl += v;
        }
        if (lane == 63) wsum[wid] = incl;
        __syncthreads();
        int waveoff = 0;
        for (int w = 0; w < wid; ++w) waveoff += wsum[w];
        const int excl = waveoff + incl - cnt;

        float4* lrow = (float4*)(labels + row * Ln + t0);
        float4* irow = (float4*)(inv + row * Ln + t0);

        float lb[16], iv[16];
#pragma unroll
        for (int j = 0; j < 16; ++j) {
            lb[j] = (float)lv[j];
            iv[j] = (float)(excl + invloc[j] - 1);
        }
#pragma unroll
        for (int q = 0; q < 4; ++q) {
            nt_store4(lrow + q, make_float4(lb[q*4], lb[q*4+1], lb[q*4+2], lb[q*4+3]));
            nt_store4(irow + q, make_float4(iv[q*4], iv[q*4+1], iv[q*4+2], iv[q*4+3]));
        }

        // scatter run-start values into LDS ded row
        run = prevlab; int c2 = 0;
#pragma unroll
        for (int j = 0; j < 16; ++j) {
            if (lv[j] != run) {
                sded[excl + c2] = (float)lv[j];
                ++c2;
            }
            run = lv[j];
        }
        __syncthreads();
        // coalesced streaming writeout of the ded row
        float4* drow4 = (float4*)(ded + row * Ln);
        for (int i = tid; i < Ln / 4; i += 256) nt_store4(drow4 + i, sded4[i]);
        __syncthreads();   // LDS about to be reused by probs phase
    } else {
        pbase = (bid - Bn) * P_PROBS;
        pcnt = P_PROBS;
    }

    // ================= probs phase (all blocks) =================
    {
        const float4* W4 = (const float4*)W;
        for (int i = tid; i < NU * Dn / 4; i += 256) sW4[i] = W4[i];
        for (int i = tid; i < pcnt; i += 256) sx[i] = x[pbase + i];
        __syncthreads();
        if (tid < NU) {
            float ss = 0.f;
#pragma unroll
            for (int d = 0; d < Dn; ++d) { float v = sW[tid * Dn + d]; ss += v * v; }
            float scale = fminf(1.0f, 1.0f / fmaxf(sqrtf(ss), 1e-12f));
#pragma unroll
            for (int d = 0; d < Dn; ++d) sW[tid * Dn + d] *= scale;
        }
        __syncthreads();

        if (tid < 250) {
            const int pl = tid / 10;                 // 0..24, loop-invariant
            const int c  = tid - pl * 10;            // 0..9,  loop-invariant
            float4* outp = (float4*)probs + (size_t)pbase * 10 + tid;
            const int nfull = pcnt / 25;
            const int* sxp = sx + pl;
            for (int kk = 0; kk < nfull; ++kk) {
                int u = sxp[kk * 25];                // LDS broadcast (10 lanes share)
                nt_store4(outp, sW4[u * 10 + c]);
                outp += 250;
            }
            const int rem = pcnt - nfull * 25;
            if (pl < rem) {
                int u = sxp[nfull * 25];
                nt_store4(outp, sW4[u * 10 + c]);
            }
        }
    }
}

extern "C" void kernel_launch(void* const* d_in, const int* in_sizes, int n_in,
                              void* d_out, int out_size, void* d_ws, size_t ws_size,
                              hipStream_t stream) {
    const int* x = (const int*)d_in[0];        // [256,4096] int32
    const float* W = (const float*)d_in[1];    // [101,40] f32
    float* out = (float*)d_out;

    fused_kernel<<<NBLK, 256, 0, stream>>>(x, W, out);
}

// Round 7
// 37.323 us; speedup vs baseline: 1.3476x; 1.3476x over previous
//
#include <hip/hip_runtime.h>

static constexpr int Bn = 256;
static constexpr int Ln = 4096;
static constexpr int Dn = 40;     // output dim
static constexpr int NU = 101;    // number of embedding rows
static constexpr float PADF = 39.0f;

static constexpr int NBLK = 2048;        // 8 blocks/CU, all co-resident
static constexpr int P_PROBS = 560;      // positions per pure-probs block
static constexpr int P_RLE   = 176;      // positions per rle block
static_assert((NBLK - Bn) * P_PROBS + Bn * P_RLE == Bn * Ln, "position split must cover exactly");

static constexpr int SMEM_BYTES = 18432;

// One fused kernel, 2048 blocks:
//   blocks [0, Bn)    : RLE for row bid (labels/ded/inv), then small probs share
//   blocks [Bn, 2048) : probs share only
// Default (write-back) stores: R6 measured nontemporal stores at 50.3 us vs
// 37.2 us write-back — L2 write-combining is load-bearing for this stream.
__global__ __launch_bounds__(256) void fused_kernel(const int* __restrict__ x,
                                                    const float* __restrict__ W,
                                                    float* __restrict__ out) {
    __shared__ __align__(16) char smem[SMEM_BYTES];
    // probs-phase layout:
    float4* sW4 = (float4*)smem;                     // 1010 f4 = 16160 B (scaled table)
    float*  sW  = (float*)smem;
    int*    sx  = (int*)(smem + 16160);              // up to 568 ints (needs <= 560)
    // rle-phase layout (aliased; phases separated by barriers):
    float*  sded  = (float*)smem;                    // 4096 f32 = 16384 B
    float4* sded4 = (float4*)smem;
    int*    slab  = (int*)(smem + 16384);            // 101 ints
    int*    wsum  = (int*)(smem + 16384 + 101 * 4);  // 4 ints

    float* probs  = out;
    float* labels = out + (size_t)Bn * Ln * Dn;
    float* ded    = labels + (size_t)Bn * Ln;
    float* inv    = ded + (size_t)Bn * Ln;

    const int tid = threadIdx.x;
    const int bid = blockIdx.x;

    int pbase, pcnt;
    if (bid < Bn) {
        // ================= RLE phase (row = bid) =================
        pbase = (NBLK - Bn) * P_PROBS + bid * P_RLE;
        pcnt = P_RLE;

        if (tid < NU) {
            const float* wr = W + tid * Dn;
            float ss = 0.f;
#pragma unroll
            for (int d = 0; d < Dn; ++d) { float v = wr[d]; ss += v * v; }
            float scale = fminf(1.0f, 1.0f / fmaxf(sqrtf(ss), 1e-12f));
            float best = -3.4e38f; int bi = 0;
#pragma unroll
            for (int d = 0; d < Dn; ++d) {
                float v = wr[d] * scale;               // argmax on SCALED values
                if (v > best) { best = v; bi = d; }    // strict > == jnp first-max
            }
            slab[tid] = bi;
        }
        {
            const float4 padv = make_float4(PADF, PADF, PADF, PADF);
            for (int i = tid; i < Ln / 4; i += 256) sded4[i] = padv;
        }
        __syncthreads();

        const int row = bid;
        const int* xr = x + row * Ln;
        const int t0 = tid * 16;

        int xv[16];
        const int4* xp = (const int4*)(xr + t0);
#pragma unroll
        for (int q = 0; q < 4; ++q) {
            int4 a = xp[q];
            xv[q * 4 + 0] = a.x; xv[q * 4 + 1] = a.y;
            xv[q * 4 + 2] = a.z; xv[q * 4 + 3] = a.w;
        }
        const int prevlab = (tid == 0) ? -1 : slab[xr[t0 - 1]];

        int lv[16]; int invloc[16];
        int run = prevlab; int cnt = 0;
#pragma unroll
        for (int j = 0; j < 16; ++j) {
            lv[j] = slab[xv[j]];
            cnt += (lv[j] != run) ? 1 : 0;
            invloc[j] = cnt;
            run = lv[j];
        }

        const int lane = tid & 63;
        const int wid = tid >> 6;
        int incl = cnt;
#pragma unroll
        for (int off = 1; off < 64; off <<= 1) {
            int v = __shfl_up(incl, off, 64);
            if (lane >= off) incl += v;
        }
        if (lane == 63) wsum[wid] = incl;
        __syncthreads();
        int waveoff = 0;
        for (int w = 0; w < wid; ++w) waveoff += wsum[w];
        const int excl = waveoff + incl - cnt;

        float* lrow = labels + row * Ln + t0;
        float* irow = inv + row * Ln + t0;

        float lb[16], iv[16];
#pragma unroll
        for (int j = 0; j < 16; ++j) {
            lb[j] = (float)lv[j];
            iv[j] = (float)(excl + invloc[j] - 1);
        }
#pragma unroll
        for (int q = 0; q < 4; ++q) {
            ((float4*)lrow)[q] = make_float4(lb[q*4], lb[q*4+1], lb[q*4+2], lb[q*4+3]);
            ((float4*)irow)[q] = make_float4(iv[q*4], iv[q*4+1], iv[q*4+2], iv[q*4+3]);
        }

        // scatter run-start values into LDS ded row
        run = prevlab; int c2 = 0;
#pragma unroll
        for (int j = 0; j < 16; ++j) {
            if (lv[j] != run) {
                sded[excl + c2] = (float)lv[j];
                ++c2;
            }
            run = lv[j];
        }
        __syncthreads();
        // coalesced writeout of the ded row
        float4* drow4 = (float4*)(ded + row * Ln);
        for (int i = tid; i < Ln / 4; i += 256) drow4[i] = sded4[i];
        __syncthreads();   // LDS about to be reused by probs phase
    } else {
        pbase = (bid - Bn) * P_PROBS;
        pcnt = P_PROBS;
    }

    // ================= probs phase (all blocks) =================
    {
        const float4* W4 = (const float4*)W;
        for (int i = tid; i < NU * Dn / 4; i += 256) sW4[i] = W4[i];
        for (int i = tid; i < pcnt; i += 256) sx[i] = x[pbase + i];
        __syncthreads();
        if (tid < NU) {
            float ss = 0.f;
#pragma unroll
            for (int d = 0; d < Dn; ++d) { float v = sW[tid * Dn + d]; ss += v * v; }
            float scale = fminf(1.0f, 1.0f / fmaxf(sqrtf(ss), 1e-12f));
#pragma unroll
            for (int d = 0; d < Dn; ++d) sW[tid * Dn + d] *= scale;
        }
        __syncthreads();

        if (tid < 250) {
            const int pl = tid / 10;                 // 0..24, loop-invariant
            const int c  = tid - pl * 10;            // 0..9,  loop-invariant
            float4* outp = (float4*)probs + (size_t)pbase * 10 + tid;
            const int nfull = pcnt / 25;
            const int* sxp = sx + pl;
            for (int kk = 0; kk < nfull; ++kk) {
                int u = sxp[kk * 25];                // LDS broadcast (10 lanes share)
                *outp = sW4[u * 10 + c];
                outp += 250;
            }
            const int rem = pcnt - nfull * 25;
            if (pl < rem) {
                int u = sxp[nfull * 25];
                *outp = sW4[u * 10 + c];
            }
        }
    }
}

extern "C" void kernel_launch(void* const* d_in, const int* in_sizes, int n_in,
                              void* d_out, int out_size, void* d_ws, size_t ws_size,
                              hipStream_t stream) {
    const int* x = (const int*)d_in[0];        // [256,4096] int32
    const float* W = (const float*)d_in[1];    // [101,40] f32
    float* out = (float*)d_out;

    fused_kernel<<<NBLK, 256, 0, stream>>>(x, W, out);
}